// Round 1
// baseline (140.228 us; speedup 1.0000x reference)
//
#include <hip/hip_runtime.h>
#include <math.h>

#define D      256
#define NSEC   10
#define EPS    1e-6f
#define SLICE  0.1f

// ws float layout
#define WS_SUMS 0              // [2560) per-sector sums
#define WS_CNT  (NSEC * D)     // [2560,2570) per-sector counts
#define WS_DIST (NSEC * D + NSEC)        // [2570] distance accumulator
#define WS_CENT (NSEC * D + NSEC + 6)    // [2576,5136) centers (16B aligned)
#define WS_ZERO_FLOATS (NSEC * D + NSEC + 1)

__global__ void k_zero(float* __restrict__ ws) {
    int i = blockIdx.x * blockDim.x + threadIdx.x;
    if (i < WS_ZERO_FLOATS) ws[i] = 0.f;
}

__global__ __launch_bounds__(256) void k_sums(const float* __restrict__ emb,
                                              const int* __restrict__ sec,
                                              float* __restrict__ ws, int nrows) {
    const int lane = threadIdx.x & 63;
    const int wid  = threadIdx.x >> 6;          // 0..3
    const int gw   = blockIdx.x * 4 + wid;      // global wave id
    const int nw   = gridDim.x * 4;

    float4 acc[NSEC];
    float  cnt[NSEC];
#pragma unroll
    for (int s = 0; s < NSEC; ++s) { acc[s] = make_float4(0.f, 0.f, 0.f, 0.f); cnt[s] = 0.f; }

    for (int r = gw; r < nrows; r += nw) {
        const int s = __builtin_amdgcn_readfirstlane(sec[r]);   // wave-uniform sector -> SGPR
        const float4 v = *reinterpret_cast<const float4*>(emb + (size_t)r * D + lane * 4);
#pragma unroll
        for (int ss = 0; ss < NSEC; ++ss) {
            if (s == ss) {   // scalar branch; acc index stays compile-time constant
                acc[ss].x += v.x; acc[ss].y += v.y; acc[ss].z += v.z; acc[ss].w += v.w;
                cnt[ss] += 1.f;
            }
        }
    }

    __shared__ float lsum[NSEC * D];
    __shared__ float lcnt[NSEC];
    for (int i = threadIdx.x; i < NSEC * D; i += 256) lsum[i] = 0.f;
    if (threadIdx.x < NSEC) lcnt[threadIdx.x] = 0.f;
    __syncthreads();

    // 4 serialized wave phases: no LDS atomics, no intra-wave address overlap
    for (int w = 0; w < 4; ++w) {
        if (wid == w) {
#pragma unroll
            for (int ss = 0; ss < NSEC; ++ss) {
                float* p = &lsum[ss * D + lane * 4];
                p[0] += acc[ss].x; p[1] += acc[ss].y; p[2] += acc[ss].z; p[3] += acc[ss].w;
                if (lane == 0) lcnt[ss] += cnt[ss];
            }
        }
        __syncthreads();
    }

#pragma unroll
    for (int ss = 0; ss < NSEC; ++ss)
        atomicAdd(&ws[WS_SUMS + ss * D + threadIdx.x], lsum[ss * D + threadIdx.x]);
    if (threadIdx.x < NSEC)
        atomicAdd(&ws[WS_CNT + threadIdx.x], lcnt[threadIdx.x]);
}

__global__ void k_centers(float* __restrict__ ws) {
    int i = blockIdx.x * blockDim.x + threadIdx.x;
    if (i < NSEC * D) {
        int s = i / D;
        ws[WS_CENT + i] = ws[WS_SUMS + i] / ws[WS_CNT + s];
    }
}

__global__ __launch_bounds__(256) void k_dist(const float* __restrict__ temb,
                                              const float* __restrict__ tsl,
                                              float* __restrict__ ws, int nrows) {
    __shared__ float lc[NSEC * D];
    for (int i = threadIdx.x; i < NSEC * D; i += 256) lc[i] = ws[WS_CENT + i];
    __syncthreads();

    const int lane = threadIdx.x & 63;
    const int wid  = threadIdx.x >> 6;
    const int gw   = blockIdx.x * 4 + wid;
    const int nw   = gridDim.x * 4;

    float wacc = 0.f;
    for (int r = gw; r < nrows; r += nw) {
        const float si = tsl[r];
        int s = (int)floorf(si / SLICE);          // match reference: divide, floor, clip
        s = s < 0 ? 0 : (s > NSEC - 1 ? NSEC - 1 : s);
        const float4 v = *reinterpret_cast<const float4*>(temb + (size_t)r * D + lane * 4);
        const float4 c = *reinterpret_cast<const float4*>(&lc[s * D + lane * 4]);
        const float dx = v.x - c.x + EPS;
        const float dy = v.y - c.y + EPS;
        const float dz = v.z - c.z + EPS;
        const float dw = v.w - c.w + EPS;
        float loc = dx * dx + dy * dy + dz * dz + dw * dw;
#pragma unroll
        for (int off = 32; off >= 1; off >>= 1) loc += __shfl_xor(loc, off, 64);
        if (lane == 0) wacc += sqrtf(loc);
    }

    __shared__ float wsum[4];
    if (lane == 0) wsum[wid] = wacc;
    __syncthreads();
    if (threadIdx.x == 0)
        atomicAdd(&ws[WS_DIST], wsum[0] + wsum[1] + wsum[2] + wsum[3]);
}

__global__ void k_final(const float* __restrict__ ws, float* __restrict__ out, float invN) {
    out[0] = ws[WS_DIST] * invN;
}

extern "C" void kernel_launch(void* const* d_in, const int* in_sizes, int n_in,
                              void* d_out, int out_size, void* d_ws, size_t ws_size,
                              hipStream_t stream) {
    const float* semb = (const float*)d_in[0];   // [nS, 256] f32
    const int*   ssec = (const int*)d_in[1];     // [nS] i32
    const float* temb = (const float*)d_in[2];   // [nT, 256] f32
    const float* tsl  = (const float*)d_in[3];   // [nT] f32
    float* ws  = (float*)d_ws;
    float* out = (float*)d_out;
    const int nS = in_sizes[1];
    const int nT = in_sizes[3];

    hipLaunchKernelGGL(k_zero, dim3((WS_ZERO_FLOATS + 255) / 256), dim3(256), 0, stream, ws);
    hipLaunchKernelGGL(k_sums, dim3(512), dim3(256), 0, stream, semb, ssec, ws, nS);
    hipLaunchKernelGGL(k_centers, dim3((NSEC * D + 255) / 256), dim3(256), 0, stream, ws);
    hipLaunchKernelGGL(k_dist, dim3(512), dim3(256), 0, stream, temb, tsl, ws, nT);
    hipLaunchKernelGGL(k_final, dim3(1), dim3(1), 0, stream, ws, out, 1.0f / (float)nT);
}

// Round 2
// 101.352 us; speedup vs baseline: 1.3836x; 1.3836x over previous
//
#include <hip/hip_runtime.h>
#include <math.h>

#define D      256
#define NSEC   10
#define EPS    1e-6f
#define SLICE  0.1f

// ws float layout
#define WS_SUMS 0                      // [0,2560) per-sector sums
#define WS_CNT  (NSEC * D)             // [2560,2570) per-sector counts
#define WS_DIST (NSEC * D + NSEC)      // [2570] distance accumulator
#define WS_DONE (NSEC * D + NSEC + 1)  // [2571] done-block counter (as uint bits)
#define WS_ZERO_FLOATS (NSEC * D + NSEC + 2)

__global__ void k_zero(float* __restrict__ ws) {
    int i = blockIdx.x * blockDim.x + threadIdx.x;
    if (i < WS_ZERO_FLOATS) ws[i] = 0.f;
}

__global__ __launch_bounds__(256) void k_sums(const float* __restrict__ emb,
                                              const int* __restrict__ sec,
                                              float* __restrict__ ws, int nrows) {
    const int lane = threadIdx.x & 63;
    const int wid  = threadIdx.x >> 6;          // 0..3
    const int gw   = blockIdx.x * 4 + wid;      // global wave id
    const int nw   = gridDim.x * 4;

    float4 acc[NSEC];
    float  cnt[NSEC];
#pragma unroll
    for (int s = 0; s < NSEC; ++s) { acc[s] = make_float4(0.f, 0.f, 0.f, 0.f); cnt[s] = 0.f; }

    const float* ep = emb + (size_t)lane * 4;

    auto accum = [&](int sv, float4 v) {
        const int s = __builtin_amdgcn_readfirstlane(sv);  // wave-uniform -> SGPR branch
#pragma unroll
        for (int ss = 0; ss < NSEC; ++ss) {
            if (s == ss) {   // scalar branch; acc index compile-time constant (no scratch)
                acc[ss].x += v.x; acc[ss].y += v.y; acc[ss].z += v.z; acc[ss].w += v.w;
                cnt[ss] += 1.f;
            }
        }
    };

    int r = gw;
    // unroll-4: 4 KB in flight per wave hides HBM latency
    for (; r + 3 * nw < nrows; r += 4 * nw) {
        const int s0 = sec[r];
        const int s1 = sec[r + nw];
        const int s2 = sec[r + 2 * nw];
        const int s3 = sec[r + 3 * nw];
        const float4 v0 = *reinterpret_cast<const float4*>(ep + (size_t)r * D);
        const float4 v1 = *reinterpret_cast<const float4*>(ep + (size_t)(r + nw) * D);
        const float4 v2 = *reinterpret_cast<const float4*>(ep + (size_t)(r + 2 * nw) * D);
        const float4 v3 = *reinterpret_cast<const float4*>(ep + (size_t)(r + 3 * nw) * D);
        accum(s0, v0); accum(s1, v1); accum(s2, v2); accum(s3, v3);
    }
    for (; r < nrows; r += nw)
        accum(sec[r], *reinterpret_cast<const float4*>(ep + (size_t)r * D));

    __shared__ float lsum[NSEC * D];
    __shared__ float lcnt[NSEC];
    for (int i = threadIdx.x; i < NSEC * D; i += 256) lsum[i] = 0.f;
    if (threadIdx.x < NSEC) lcnt[threadIdx.x] = 0.f;
    __syncthreads();

    // 4 serialized wave phases: no LDS atomics, no intra-wave address overlap
    for (int w = 0; w < 4; ++w) {
        if (wid == w) {
#pragma unroll
            for (int ss = 0; ss < NSEC; ++ss) {
                float* p = &lsum[ss * D + lane * 4];
                p[0] += acc[ss].x; p[1] += acc[ss].y; p[2] += acc[ss].z; p[3] += acc[ss].w;
                if (lane == 0) lcnt[ss] += cnt[ss];
            }
        }
        __syncthreads();
    }

#pragma unroll
    for (int ss = 0; ss < NSEC; ++ss)
        atomicAdd(&ws[WS_SUMS + ss * D + threadIdx.x], lsum[ss * D + threadIdx.x]);
    if (threadIdx.x < NSEC)
        atomicAdd(&ws[WS_CNT + threadIdx.x], lcnt[threadIdx.x]);
}

// Fused: centers (per-block, from global sums) + distances + mean (last block writes out)
__global__ __launch_bounds__(256) void k_dist(const float* __restrict__ temb,
                                              const float* __restrict__ tsl,
                                              float* __restrict__ ws,
                                              float* __restrict__ out,
                                              int nrows, float invN) {
    __shared__ float lc[NSEC * D];
    for (int i = threadIdx.x; i < NSEC * D; i += 256) {
        const int s = i >> 8;  // i / D
        lc[i] = ws[WS_SUMS + i] / ws[WS_CNT + s];
    }
    __syncthreads();

    const int lane = threadIdx.x & 63;
    const int wid  = threadIdx.x >> 6;
    const int gw   = blockIdx.x * 4 + wid;
    const int nw   = gridDim.x * 4;

    const float* tp = temb + (size_t)lane * 4;

    auto rowdist = [&](float si, float4 v) -> float {
        int s = (int)floorf(si / SLICE);   // exact reference semantics: divide, floor, clip
        s = s < 0 ? 0 : (s > NSEC - 1 ? NSEC - 1 : s);
        const float4 c = *reinterpret_cast<const float4*>(&lc[s * D + lane * 4]);
        const float dx = v.x - c.x + EPS;
        const float dy = v.y - c.y + EPS;
        const float dz = v.z - c.z + EPS;
        const float dw = v.w - c.w + EPS;
        float loc = dx * dx + dy * dy + dz * dz + dw * dw;
#pragma unroll
        for (int off = 32; off >= 1; off >>= 1) loc += __shfl_xor(loc, off, 64);
        return loc;   // full row sum-of-squares, replicated across lanes
    };

    float wacc = 0.f;
    int r = gw;
    for (; r + 3 * nw < nrows; r += 4 * nw) {
        const float t0 = tsl[r];
        const float t1 = tsl[r + nw];
        const float t2 = tsl[r + 2 * nw];
        const float t3 = tsl[r + 3 * nw];
        const float4 v0 = *reinterpret_cast<const float4*>(tp + (size_t)r * D);
        const float4 v1 = *reinterpret_cast<const float4*>(tp + (size_t)(r + nw) * D);
        const float4 v2 = *reinterpret_cast<const float4*>(tp + (size_t)(r + 2 * nw) * D);
        const float4 v3 = *reinterpret_cast<const float4*>(tp + (size_t)(r + 3 * nw) * D);
        float l0 = rowdist(t0, v0);
        float l1 = rowdist(t1, v1);
        float l2 = rowdist(t2, v2);
        float l3 = rowdist(t3, v3);
        if (lane == 0) wacc += sqrtf(l0) + sqrtf(l1) + sqrtf(l2) + sqrtf(l3);
    }
    for (; r < nrows; r += nw) {
        float l = rowdist(tsl[r], *reinterpret_cast<const float4*>(tp + (size_t)r * D));
        if (lane == 0) wacc += sqrtf(l);
    }

    __shared__ float wsum[4];
    if (lane == 0) wsum[wid] = wacc;
    __syncthreads();
    if (threadIdx.x == 0) {
        atomicAdd(&ws[WS_DIST], wsum[0] + wsum[1] + wsum[2] + wsum[3]);
        __threadfence();   // make the add visible device-wide before signaling done
        unsigned prev = atomicAdd(reinterpret_cast<unsigned*>(&ws[WS_DONE]), 1u);
        if (prev == gridDim.x - 1) {
            // last block: read total via atomic (device-scope coherent), write mean
            const float tot = atomicAdd(&ws[WS_DIST], 0.0f);
            out[0] = tot * invN;
        }
    }
}

extern "C" void kernel_launch(void* const* d_in, const int* in_sizes, int n_in,
                              void* d_out, int out_size, void* d_ws, size_t ws_size,
                              hipStream_t stream) {
    const float* semb = (const float*)d_in[0];   // [nS, 256] f32
    const int*   ssec = (const int*)d_in[1];     // [nS] i32
    const float* temb = (const float*)d_in[2];   // [nT, 256] f32
    const float* tsl  = (const float*)d_in[3];   // [nT] f32
    float* ws  = (float*)d_ws;
    float* out = (float*)d_out;
    const int nS = in_sizes[1];
    const int nT = in_sizes[3];

    hipLaunchKernelGGL(k_zero, dim3((WS_ZERO_FLOATS + 255) / 256), dim3(256), 0, stream, ws);
    hipLaunchKernelGGL(k_sums, dim3(512), dim3(256), 0, stream, semb, ssec, ws, nS);
    hipLaunchKernelGGL(k_dist, dim3(512), dim3(256), 0, stream, temb, tsl, ws, out,
                       nT, 1.0f / (float)nT);
}